// Round 11
// baseline (657.638 us; speedup 1.0000x reference)
//
#include <hip/hip_runtime.h>
#include <math.h>

#define DOUT 64

// ---------------------------------------------------------------------------
// GCN(5) + LSTM(1 step) + FC head, f32, MI355X.
// h0=c0=0  =>  f-gate and W_hh are dead; c1 = i*g.
// hWs/agg live in QUARTER layout [q][node][16] (q = feature quarter) so each
// gather pass's source slice (3.2 MB) is L2-resident per XCD.
// ---------------------------------------------------------------------------

__global__ __launch_bounds__(256) void k_count(const int* __restrict__ col,
                                               int* __restrict__ cnt, int e) {
    int i = blockIdx.x * 256 + threadIdx.x;
    if (i < e) atomicAdd(&cnt[col[i]], 1);
}

// ---- hierarchical exclusive scan of cnt[0..n): 1024 nodes/block, <=64 blocks.

__global__ __launch_bounds__(256) void k_scanA(const int* __restrict__ cnt,
                                               int* __restrict__ bsum, int n) {
    __shared__ int part[256];
    const int t = threadIdx.x;
    const int base = blockIdx.x * 1024 + t * 4;
    int s = 0;
    #pragma unroll
    for (int i = 0; i < 4; i++) { int idx = base + i; if (idx < n) s += cnt[idx]; }
    part[t] = s;
    __syncthreads();
    #pragma unroll
    for (int off = 128; off > 0; off >>= 1) {
        if (t < off) part[t] += part[t + off];
        __syncthreads();
    }
    if (t == 0) bsum[blockIdx.x] = part[0];
}

__global__ __launch_bounds__(64) void k_scanB(const int* __restrict__ bsum,
                                              int* __restrict__ boff, int nb) {
    const int t = threadIdx.x;          // single wave of 64
    int val = (t < nb) ? bsum[t] : 0;
    const int own = val;
    #pragma unroll
    for (int off = 1; off < 64; off <<= 1) {
        int v = __shfl_up(val, off);
        if (t >= off) val += v;
    }
    if (t < nb) boff[t] = val - own;    // exclusive
}

__global__ __launch_bounds__(256) void k_scanC(const int* __restrict__ cnt,
                                               const int* __restrict__ boff,
                                               int* __restrict__ rowptr,
                                               int* __restrict__ cursor,
                                               float* __restrict__ dinv,
                                               int n, int e_total) {
    __shared__ int part[256];
    const int t = threadIdx.x;
    const int base = blockIdx.x * 1024 + t * 4;
    int c[4];
    int s = 0;
    #pragma unroll
    for (int i = 0; i < 4; i++) {
        int idx = base + i;
        c[i] = (idx < n) ? cnt[idx] : 0;
        s += c[i];
    }
    part[t] = s;
    __syncthreads();
    for (int off = 1; off < 256; off <<= 1) {
        int v = 0;
        if (t >= off) v = part[t - off];
        __syncthreads();
        if (t >= off) part[t] += v;
        __syncthreads();
    }
    int run = boff[blockIdx.x] + ((t > 0) ? part[t - 1] : 0);  // exclusive base
    #pragma unroll
    for (int i = 0; i < 4; i++) {
        int idx = base + i;
        if (idx < n) {
            rowptr[idx] = run;
            cursor[idx] = run;
            dinv[idx] = rsqrtf((float)(c[i] + 1));   // +1 self loop
            run += c[i];
        }
    }
    if (blockIdx.x == 0 && t == 0) rowptr[n] = e_total;
}

__global__ __launch_bounds__(256) void k_fill(const int* __restrict__ row,
                                              const int* __restrict__ col,
                                              int* __restrict__ cursor,
                                              int* __restrict__ srcidx, int e) {
    int i = blockIdx.x * 256 + threadIdx.x;
    if (i < e) {
        int p = atomicAdd(&cursor[col[i]], 1);
        srcidx[p] = row[i];
    }
}

// Transpose all 5 GCN weights: WT[j][d] = W[d][j].  W1:128x64, W2..W5:64x64.
__global__ __launch_bounds__(256) void k_transp(const float* __restrict__ W1,
                                                const float* __restrict__ W2,
                                                const float* __restrict__ W3,
                                                const float* __restrict__ W4,
                                                const float* __restrict__ W5,
                                                float* __restrict__ WT) {
    int i = blockIdx.x * 256 + threadIdx.x;
    if (i < 8192) {
        int j = i >> 7, d = i & 127;
        WT[i] = W1[d * 64 + j];
    } else if (i < 24576) {
        int q = i - 8192;
        int w = q >> 12, r = q & 4095;
        int j = r >> 6, d = r & 63;
        const float* Ws = (w == 0) ? W2 : (w == 1) ? W3 : (w == 2) ? W4 : W5;
        WT[i] = Ws[d * 64 + j];
    }
}

// GEMM: hWs[node] = (relu?(X[node]) * dinv[node]) @ W.
// QIN: input X in quarter layout [q][node][16]; else row-major [node][D].
// Output always quarter layout: hWs[(qj*n + node)*16 + jc], qj=lane>>4.
template<int D, bool RELU, bool QIN>
__global__ __launch_bounds__(256) void k_gemm2(const float* __restrict__ X,
                                               const float* __restrict__ WT,
                                               const float* __restrict__ dinv,
                                               float* __restrict__ hWs, int n) {
    constexpr int D4 = D / 4;
    __shared__ float Wls[64 * D];
    __shared__ float Xls[32 * D];
    const int t = threadIdx.x;
    const int node0 = blockIdx.x * 32;
    float4* Wl4 = (float4*)Wls;
    float4* Xl4 = (float4*)Xls;

    for (int i = t; i < 64 * D4; i += 256) {
        int r = i / D4, d4 = i % D4;
        Wl4[r * D4 + (d4 ^ (r & 7))] = ((const float4*)WT)[i];
    }
    for (int i = t; i < 32 * D4; i += 256) {
        int nd = i / D4, d4 = i % D4;
        float4 v = make_float4(0.f, 0.f, 0.f, 0.f);
        int node = node0 + nd;
        if (node < n) {
            if (QIN) {
                v = ((const float4*)X)[((size_t)((d4 >> 2) * n + node)) * 4 + (d4 & 3)];
            } else {
                v = ((const float4*)X)[(size_t)node * D4 + d4];
            }
            if (RELU) {
                v.x = fmaxf(v.x, 0.f); v.y = fmaxf(v.y, 0.f);
                v.z = fmaxf(v.z, 0.f); v.w = fmaxf(v.w, 0.f);
            }
            float di = dinv[node];
            v.x *= di; v.y *= di; v.z *= di; v.w *= di;
        }
        Xl4[i] = v;
    }
    __syncthreads();

    const int wv = t >> 6, lane = t & 63;
    const int sw = lane & 7;
    float acc[8];
    #pragma unroll
    for (int q = 0; q < 8; q++) acc[q] = 0.f;

    #pragma unroll 4
    for (int d4 = 0; d4 < D4; d4++) {
        float4 w = Wl4[lane * D4 + (d4 ^ sw)];
        #pragma unroll
        for (int q = 0; q < 8; q++) {
            float4 xv = Xl4[(wv * 8 + q) * D4 + d4];
            acc[q] = fmaf(xv.w, w.w, fmaf(xv.z, w.z, fmaf(xv.y, w.y, fmaf(xv.x, w.x, acc[q]))));
        }
    }
    const int qj = lane >> 4, jc = lane & 15;
    #pragma unroll
    for (int q = 0; q < 8; q++) {
        int node = node0 + wv * 8 + q;
        if (node < n) hWs[((size_t)(qj * n + node)) * 16 + jc] = acc[q];
    }
}

// Gather, quarter-pass version. Grid = 4 * bpq blocks; blocks [q*bpq, (q+1)*bpq)
// process feature quarter q (3.2 MB hWs slice -> L2-resident while active).
// Block = 4 waves = 4 nodes. Lane = (es 0..15, f4 0..3): 16 edges/VMEM instr,
// 64 B contiguous per edge. Reduce across es via shfl_xor {4,8,16,32}.
// agg[(q*n+w)*16 + f4*4..] = (sum_src hWsq[src] + hWsq[w]) * dinv[w] + b_q.
__global__ __launch_bounds__(256) void k_gather(const int* __restrict__ rowptr,
                                                const int* __restrict__ srcidx,
                                                const float* __restrict__ dinv,
                                                const float* __restrict__ b,
                                                const float* __restrict__ hWs,
                                                float* __restrict__ agg,
                                                int n, int bpq) {
    const int t = threadIdx.x;
    const int q = blockIdx.x / bpq;
    int w = (blockIdx.x - q * bpq) * 4 + (t >> 6);
    if (w >= n) return;
    w = __builtin_amdgcn_readfirstlane(w);
    const int lane = t & 63;
    const int f4 = lane & 3;
    const int es = lane >> 2;
    const float4* H4 = (const float4*)hWs + (size_t)q * n * 4;
    const int s = rowptr[w], e = rowptr[w + 1];
    float4 acc = make_float4(0.f, 0.f, 0.f, 0.f);
    if (es == 0) acc = H4[(size_t)w * 4 + f4];   // self loop
    for (int i = s + es; i < e; i += 16) {
        int src = srcidx[i];
        float4 v = H4[(size_t)src * 4 + f4];
        acc.x += v.x; acc.y += v.y; acc.z += v.z; acc.w += v.w;
    }
    #pragma unroll
    for (int off = 4; off < 64; off <<= 1) {
        acc.x += __shfl_xor(acc.x, off);
        acc.y += __shfl_xor(acc.y, off);
        acc.z += __shfl_xor(acc.z, off);
        acc.w += __shfl_xor(acc.w, off);
    }
    if (es == 0) {
        float di = dinv[w];
        float4 bv = ((const float4*)b)[q * 4 + f4];
        float4 o;
        o.x = fmaf(acc.x, di, bv.x);
        o.y = fmaf(acc.y, di, bv.y);
        o.z = fmaf(acc.z, di, bv.z);
        o.w = fmaf(acc.w, di, bv.w);
        ((float4*)agg)[((size_t)(q * n + w)) * 4 + f4] = o;
    }
}

__device__ __forceinline__ float sigm(float x) { return 1.f / (1.f + __expf(-x)); }
__device__ __forceinline__ float tanhf_(float x) { return 1.f - 2.f / (__expf(2.f * x) + 1.f); }

// LSTM + FC, v2. Block 256 = 4 waves, 32 nodes (8/wave); lane owns k={lane,64+lane}.
// LDS exactly 40960 B -> 4 blocks/CU. Gate weights in 8-way-floor XOR-swizzled
// LDS (r&7). FC via h1->LDS (132-stride pad) + 320 broadcast dot products.
// Input agg in quarter layout.
__global__ __launch_bounds__(256) void k_lstm_fc(const float* __restrict__ agg,
                                                 const float* __restrict__ W_ih,
                                                 const float* __restrict__ b_ih,
                                                 const float* __restrict__ b_hh,
                                                 const float* __restrict__ W_fc,
                                                 const float* __restrict__ b_fc,
                                                 float* __restrict__ out, int n) {
    __shared__ float smem[10240];          // 40 KB exactly
    float4* Wl4 = (float4*)smem;           // phase1: [128 r][16 f4] swizzled (32 KB)
    float4* hN4 = (float4*)(smem + 8192);  // phase1: [32 nd][16 f4] (8 KB)
    // phase2 (after sync): h1s = smem[0..4223] ([32 nd][132 pad]), wfcs = smem[4224..5503]
    const int t = threadIdx.x;
    const int wv = t >> 6, lane = t & 63;
    const int node0 = blockIdx.x * 32;
    const float4* A4 = (const float4*)agg;
    const float4* Wih4 = (const float4*)W_ih;

    // combined biases (gates i,g,o = W_ih rows 0,256,384; k = lane, 64+lane)
    const float bi0 = b_ih[lane]       + b_hh[lane];
    const float bi1 = b_ih[64 + lane]  + b_hh[64 + lane];
    const float bg0 = b_ih[256 + lane] + b_hh[256 + lane];
    const float bg1 = b_ih[320 + lane] + b_hh[320 + lane];
    const float bo0 = b_ih[384 + lane] + b_hh[384 + lane];
    const float bo1 = b_ih[448 + lane] + b_hh[448 + lane];

    // stage node features (relu of agg, quarter layout)
    for (int i = t; i < 512; i += 256) {
        int nd = i >> 4, f4i = i & 15;
        float4 v = make_float4(0.f, 0.f, 0.f, 0.f);
        int node = node0 + nd;
        if (node < n) {
            v = A4[((size_t)((f4i >> 2) * n + node)) * 4 + (f4i & 3)];
            v.x = fmaxf(v.x, 0.f); v.y = fmaxf(v.y, 0.f);
            v.z = fmaxf(v.z, 0.f); v.w = fmaxf(v.w, 0.f);
        }
        hN4[i] = v;
    }

    float ac[3][2][8];
    #pragma unroll
    for (int g = 0; g < 3; g++)
        #pragma unroll
        for (int h = 0; h < 2; h++)
            #pragma unroll
            for (int q = 0; q < 8; q++) ac[g][h][q] = 0.f;

    const int sw = lane & 7;
    #pragma unroll
    for (int g = 0; g < 3; g++) {
        __syncthreads();
        const int grow0 = (g == 0) ? 0 : ((g + 1) * 128);
        for (int i = t; i < 2048; i += 256) {
            int r = i >> 4, d4 = i & 15;
            Wl4[(r << 4) | (d4 ^ (r & 7))] = Wih4[(size_t)(grow0 + r) * 16 + d4];
        }
        __syncthreads();
        #pragma unroll 2
        for (int j = 0; j < 16; j++) {
            int js = j ^ sw;
            float4 w0 = Wl4[(lane << 4) | js];
            float4 w1 = Wl4[((64 + lane) << 4) | js];
            #pragma unroll
            for (int q = 0; q < 8; q++) {
                float4 hv = hN4[((wv * 8 + q) << 4) | j];
                ac[g][0][q] = fmaf(hv.w, w0.w, fmaf(hv.z, w0.z, fmaf(hv.y, w0.y, fmaf(hv.x, w0.x, ac[g][0][q]))));
                ac[g][1][q] = fmaf(hv.w, w1.w, fmaf(hv.z, w1.z, fmaf(hv.y, w1.y, fmaf(hv.x, w1.x, ac[g][1][q]))));
            }
        }
    }

    __syncthreads();   // gate reads done; smem free for h1s / wfcs

    #pragma unroll
    for (int q = 0; q < 8; q++) {
        int nd = wv * 8 + q;
        float gi0 = ac[0][0][q] + bi0, gg0 = ac[1][0][q] + bg0, go0 = ac[2][0][q] + bo0;
        float gi1 = ac[0][1][q] + bi1, gg1 = ac[1][1][q] + bg1, go1 = ac[2][1][q] + bo1;
        float h1a = sigm(go0) * tanhf_(sigm(gi0) * tanhf_(gg0));
        float h1b = sigm(go1) * tanhf_(sigm(gi1) * tanhf_(gg1));
        smem[nd * 132 + lane]      = h1a;   // k = lane
        smem[nd * 132 + 64 + lane] = h1b;   // k = 64+lane
    }
    float* wfcs = smem + 4224;
    for (int i = t; i < 1280; i += 256) wfcs[i] = W_fc[i];
    __syncthreads();

    // FC: 320 outputs (32 nodes x 10 classes); h1s rows padded to 132 words.
    for (int oc = t; oc < 320; oc += 256) {
        int nd = oc & 31, c = oc >> 5;
        const float4* hrow = (const float4*)&smem[nd * 132];
        const float4* wrow = (const float4*)&wfcs[c * 128];
        float s = 0.f;
        #pragma unroll 8
        for (int k4 = 0; k4 < 32; k4++) {
            float4 h = hrow[k4], w = wrow[k4];
            s = fmaf(h.w, w.w, fmaf(h.z, w.z, fmaf(h.y, w.y, fmaf(h.x, w.x, s))));
        }
        int node = node0 + nd;
        if (node < n) out[(size_t)node * 10 + c] = s + b_fc[c];
    }
}

extern "C" void kernel_launch(void* const* d_in, const int* in_sizes, int n_in,
                              void* d_out, int out_size, void* d_ws, size_t ws_size,
                              hipStream_t stream) {
    const float* x    = (const float*)d_in[0];
    const int*   ei   = (const int*)d_in[1];
    const float* W1   = (const float*)d_in[2];
    const float* b1   = (const float*)d_in[3];
    const float* W2   = (const float*)d_in[4];
    const float* b2   = (const float*)d_in[5];
    const float* W3   = (const float*)d_in[6];
    const float* b3   = (const float*)d_in[7];
    const float* W4   = (const float*)d_in[8];
    const float* b4   = (const float*)d_in[9];
    const float* W5   = (const float*)d_in[10];
    const float* b5   = (const float*)d_in[11];
    const float* W_ih = (const float*)d_in[12];
    // d_in[13] = W_hh: dead (h0 = 0)
    const float* b_ih = (const float*)d_in[14];
    const float* b_hh = (const float*)d_in[15];
    const float* W_fc = (const float*)d_in[16];
    const float* b_fc = (const float*)d_in[17];
    float* out = (float*)d_out;

    const int N = in_sizes[0] / 128;
    const int E = in_sizes[1] / 2;
    const int* row = ei;
    const int* col = ei + E;

    // workspace layout (4-byte units, each region 16B-aligned)
    size_t off = 0;
    auto alloc = [&](size_t elems) { size_t cur = off; off += (elems + 3) & ~(size_t)3; return cur; };
    int*   base_i = (int*)d_ws;
    float* base_f = (float*)d_ws;
    int*   cnt    = base_i + alloc(N);
    int*   rowptr = base_i + alloc((size_t)N + 1);
    int*   cursor = base_i + alloc(N);
    int*   srcidx = base_i + alloc(E);
    int*   bsum   = base_i + alloc(64);
    int*   boff   = base_i + alloc(64);
    float* dinv   = base_f + alloc(N);
    float* WT     = base_f + alloc(24576);
    float* hWs    = base_f + alloc((size_t)N * 64);
    float* agg    = base_f + alloc((size_t)N * 64);
    float* WT1 = WT;
    float* WT2 = WT + 8192;
    float* WT3 = WT + 8192 + 4096;
    float* WT4 = WT + 8192 + 8192;
    float* WT5 = WT + 8192 + 12288;

    const int nbE  = (E + 255) / 256;        // 3125
    const int bpq  = (N + 3) / 4;            // gather blocks per quarter (12500)
    const int nbGa = 4 * bpq;                // 50000 (4 quarter passes)
    const int nbGe = (N + 31) / 32;          // 1563
    const int nbL  = (N + 31) / 32;          // 1563
    const int nbS  = (N + 1023) / 1024;      // 49 (must be <= 64)

    hipMemsetAsync(cnt, 0, sizeof(int) * N, stream);
    k_transp<<<96, 256, 0, stream>>>(W1, W2, W3, W4, W5, WT);
    k_count<<<nbE, 256, 0, stream>>>(col, cnt, E);
    k_scanA<<<nbS, 256, 0, stream>>>(cnt, bsum, N);
    k_scanB<<<1, 64, 0, stream>>>(bsum, boff, nbS);
    k_scanC<<<nbS, 256, 0, stream>>>(cnt, boff, rowptr, cursor, dinv, N, E);
    k_fill<<<nbE, 256, 0, stream>>>(row, col, cursor, srcidx, E);

    k_gemm2<128, false, false><<<nbGe, 256, 0, stream>>>(x, WT1, dinv, hWs, N);
    k_gather<<<nbGa, 256, 0, stream>>>(rowptr, srcidx, dinv, b1, hWs, agg, N, bpq);
    k_gemm2<64, true, true><<<nbGe, 256, 0, stream>>>(agg, WT2, dinv, hWs, N);
    k_gather<<<nbGa, 256, 0, stream>>>(rowptr, srcidx, dinv, b2, hWs, agg, N, bpq);
    k_gemm2<64, true, true><<<nbGe, 256, 0, stream>>>(agg, WT3, dinv, hWs, N);
    k_gather<<<nbGa, 256, 0, stream>>>(rowptr, srcidx, dinv, b3, hWs, agg, N, bpq);
    k_gemm2<64, true, true><<<nbGe, 256, 0, stream>>>(agg, WT4, dinv, hWs, N);
    k_gather<<<nbGa, 256, 0, stream>>>(rowptr, srcidx, dinv, b4, hWs, agg, N, bpq);
    k_gemm2<64, true, true><<<nbGe, 256, 0, stream>>>(agg, WT5, dinv, hWs, N);
    k_gather<<<nbGa, 256, 0, stream>>>(rowptr, srcidx, dinv, b5, hWs, agg, N, bpq);

    k_lstm_fc<<<nbL, 256, 0, stream>>>(agg, W_ih, b_ih, b_hh, W_fc, b_fc, out, N);
}

// Round 13
// 503.559 us; speedup vs baseline: 1.3060x; 1.3060x over previous
//
#include <hip/hip_runtime.h>
#include <math.h>

#define DOUT 64

// ---------------------------------------------------------------------------
// GCN(5) + LSTM(1 step) + FC head, f32 compute, MI355X.
// h0=c0=0  =>  f-gate and W_hh are dead; c1 = i*g.
// hWs (the gather's random-read operand, 205 MB/layer of L3 traffic) is stored
// bf16: halves the bytes through the ~2.8 TB/s random-access bottleneck.
// agg / gemm accumulation / LSTM stay f32 (one rounding per layer).
// ---------------------------------------------------------------------------

__device__ __forceinline__ unsigned short f2bf(float f) {   // RNE f32->bf16
    unsigned u = __float_as_uint(f);
    unsigned r = (u + 0x7fff + ((u >> 16) & 1)) >> 16;
    return (unsigned short)r;
}
__device__ __forceinline__ float bflo(unsigned u) { return __uint_as_float(u << 16); }
__device__ __forceinline__ float bfhi(unsigned u) { return __uint_as_float(u & 0xffff0000u); }

__global__ __launch_bounds__(256) void k_count(const int* __restrict__ col,
                                               int* __restrict__ cnt, int e) {
    int i = blockIdx.x * 256 + threadIdx.x;
    if (i < e) atomicAdd(&cnt[col[i]], 1);
}

// ---- hierarchical exclusive scan of cnt[0..n): 1024 nodes/block, <=64 blocks.

__global__ __launch_bounds__(256) void k_scanA(const int* __restrict__ cnt,
                                               int* __restrict__ bsum, int n) {
    __shared__ int part[256];
    const int t = threadIdx.x;
    const int base = blockIdx.x * 1024 + t * 4;
    int s = 0;
    #pragma unroll
    for (int i = 0; i < 4; i++) { int idx = base + i; if (idx < n) s += cnt[idx]; }
    part[t] = s;
    __syncthreads();
    #pragma unroll
    for (int off = 128; off > 0; off >>= 1) {
        if (t < off) part[t] += part[t + off];
        __syncthreads();
    }
    if (t == 0) bsum[blockIdx.x] = part[0];
}

__global__ __launch_bounds__(64) void k_scanB(const int* __restrict__ bsum,
                                              int* __restrict__ boff, int nb) {
    const int t = threadIdx.x;          // single wave of 64
    int val = (t < nb) ? bsum[t] : 0;
    const int own = val;
    #pragma unroll
    for (int off = 1; off < 64; off <<= 1) {
        int v = __shfl_up(val, off);
        if (t >= off) val += v;
    }
    if (t < nb) boff[t] = val - own;    // exclusive
}

__global__ __launch_bounds__(256) void k_scanC(const int* __restrict__ cnt,
                                               const int* __restrict__ boff,
                                               int* __restrict__ rowptr,
                                               int* __restrict__ cursor,
                                               float* __restrict__ dinv,
                                               int n, int e_total) {
    __shared__ int part[256];
    const int t = threadIdx.x;
    const int base = blockIdx.x * 1024 + t * 4;
    int c[4];
    int s = 0;
    #pragma unroll
    for (int i = 0; i < 4; i++) {
        int idx = base + i;
        c[i] = (idx < n) ? cnt[idx] : 0;
        s += c[i];
    }
    part[t] = s;
    __syncthreads();
    for (int off = 1; off < 256; off <<= 1) {
        int v = 0;
        if (t >= off) v = part[t - off];
        __syncthreads();
        if (t >= off) part[t] += v;
        __syncthreads();
    }
    int run = boff[blockIdx.x] + ((t > 0) ? part[t - 1] : 0);  // exclusive base
    #pragma unroll
    for (int i = 0; i < 4; i++) {
        int idx = base + i;
        if (idx < n) {
            rowptr[idx] = run;
            cursor[idx] = run;
            dinv[idx] = rsqrtf((float)(c[i] + 1));   // +1 self loop
            run += c[i];
        }
    }
    if (blockIdx.x == 0 && t == 0) rowptr[n] = e_total;
}

__global__ __launch_bounds__(256) void k_fill(const int* __restrict__ row,
                                              const int* __restrict__ col,
                                              int* __restrict__ cursor,
                                              int* __restrict__ srcidx, int e) {
    int i = blockIdx.x * 256 + threadIdx.x;
    if (i < e) {
        int p = atomicAdd(&cursor[col[i]], 1);
        srcidx[p] = row[i];
    }
}

// Transpose all 5 GCN weights: WT[j][d] = W[d][j].  W1:128x64, W2..W5:64x64.
__global__ __launch_bounds__(256) void k_transp(const float* __restrict__ W1,
                                                const float* __restrict__ W2,
                                                const float* __restrict__ W3,
                                                const float* __restrict__ W4,
                                                const float* __restrict__ W5,
                                                float* __restrict__ WT) {
    int i = blockIdx.x * 256 + threadIdx.x;
    if (i < 8192) {
        int j = i >> 7, d = i & 127;
        WT[i] = W1[d * 64 + j];
    } else if (i < 24576) {
        int q = i - 8192;
        int w = q >> 12, r = q & 4095;
        int j = r >> 6, d = r & 63;
        const float* Ws = (w == 0) ? W2 : (w == 1) ? W3 : (w == 2) ? W4 : W5;
        WT[i] = Ws[d * 64 + j];
    }
}

// GEMM: hWs[node] = bf16( (relu?(X[node]) * dinv[node]) @ W ).
// W rows in LDS with r&7 XOR swizzle (8-way b128 floor).
template<int D, bool RELU>
__global__ __launch_bounds__(256) void k_gemm2(const float* __restrict__ X,
                                               const float* __restrict__ WT,
                                               const float* __restrict__ dinv,
                                               unsigned short* __restrict__ hWs, int n) {
    constexpr int D4 = D / 4;
    __shared__ float Wls[64 * D];
    __shared__ float Xls[32 * D];
    const int t = threadIdx.x;
    const int node0 = blockIdx.x * 32;
    float4* Wl4 = (float4*)Wls;
    float4* Xl4 = (float4*)Xls;

    for (int i = t; i < 64 * D4; i += 256) {
        int r = i / D4, d4 = i % D4;
        Wl4[r * D4 + (d4 ^ (r & 7))] = ((const float4*)WT)[i];
    }
    for (int i = t; i < 32 * D4; i += 256) {
        int nd = i / D4, d4 = i % D4;
        float4 v = make_float4(0.f, 0.f, 0.f, 0.f);
        int node = node0 + nd;
        if (node < n) {
            v = ((const float4*)X)[(size_t)node * D4 + d4];
            if (RELU) {
                v.x = fmaxf(v.x, 0.f); v.y = fmaxf(v.y, 0.f);
                v.z = fmaxf(v.z, 0.f); v.w = fmaxf(v.w, 0.f);
            }
            float di = dinv[node];
            v.x *= di; v.y *= di; v.z *= di; v.w *= di;
        }
        Xl4[i] = v;
    }
    __syncthreads();

    const int wv = t >> 6, lane = t & 63;
    const int sw = lane & 7;
    float acc[8];
    #pragma unroll
    for (int q = 0; q < 8; q++) acc[q] = 0.f;

    #pragma unroll 4
    for (int d4 = 0; d4 < D4; d4++) {
        float4 w = Wl4[lane * D4 + (d4 ^ sw)];
        #pragma unroll
        for (int q = 0; q < 8; q++) {
            float4 xv = Xl4[(wv * 8 + q) * D4 + d4];
            acc[q] = fmaf(xv.w, w.w, fmaf(xv.z, w.z, fmaf(xv.y, w.y, fmaf(xv.x, w.x, acc[q]))));
        }
    }
    #pragma unroll
    for (int q = 0; q < 8; q++) {
        int node = node0 + wv * 8 + q;
        if (node < n) hWs[(size_t)node * 64 + lane] = f2bf(acc[q]);  // 2B/lane, coalesced
    }
}

// Gather: agg[c] = (sum_{in-edges} hWs[src] + hWs[c]) * dinv[c] + b.   (hWs bf16)
// Wave per node; lane = (es 0..3, f4 0..15): 4 edges x 128 B segments per
// VMEM instr, 8 B (4 bf16) per lane. 2-way unroll = 2 chains in flight.
__global__ __launch_bounds__(256) void k_gather(const int* __restrict__ rowptr,
                                                const int* __restrict__ srcidx,
                                                const float* __restrict__ dinv,
                                                const float* __restrict__ b,
                                                const unsigned short* __restrict__ hWs,
                                                float* __restrict__ agg, int n) {
    const int t = threadIdx.x;
    int w = (blockIdx.x * 256 + t) >> 6;
    if (w >= n) return;
    w = __builtin_amdgcn_readfirstlane(w);
    const int lane = t & 63;
    const int f4 = lane & 15;
    const int es = lane >> 4;
    const uint2* H2 = (const uint2*)hWs;   // row = 16 uint2 (64 bf16 = 128 B)
    const int s = rowptr[w], e = rowptr[w + 1];
    float4 acc0 = make_float4(0.f, 0.f, 0.f, 0.f);
    float4 acc1 = make_float4(0.f, 0.f, 0.f, 0.f);
    if (es == 0) {   // self loop
        uint2 v = H2[(size_t)w * 16 + f4];
        acc0.x = bflo(v.x); acc0.y = bfhi(v.x); acc0.z = bflo(v.y); acc0.w = bfhi(v.y);
    }
    int i = s + es;
    for (; i + 4 < e; i += 8) {
        int s0 = srcidx[i];
        int s1 = srcidx[i + 4];
        uint2 v0 = H2[(size_t)s0 * 16 + f4];
        uint2 v1 = H2[(size_t)s1 * 16 + f4];
        acc0.x += bflo(v0.x); acc0.y += bfhi(v0.x); acc0.z += bflo(v0.y); acc0.w += bfhi(v0.y);
        acc1.x += bflo(v1.x); acc1.y += bfhi(v1.x); acc1.z += bflo(v1.y); acc1.w += bfhi(v1.y);
    }
    if (i < e) {
        int s0 = srcidx[i];
        uint2 v0 = H2[(size_t)s0 * 16 + f4];
        acc0.x += bflo(v0.x); acc0.y += bfhi(v0.x); acc0.z += bflo(v0.y); acc0.w += bfhi(v0.y);
    }
    acc0.x += acc1.x; acc0.y += acc1.y; acc0.z += acc1.z; acc0.w += acc1.w;
    #pragma unroll
    for (int off = 16; off < 64; off <<= 1) {
        acc0.x += __shfl_xor(acc0.x, off);
        acc0.y += __shfl_xor(acc0.y, off);
        acc0.z += __shfl_xor(acc0.z, off);
        acc0.w += __shfl_xor(acc0.w, off);
    }
    if (es == 0) {
        float di = dinv[w];
        float4 bv = ((const float4*)b)[f4];
        float4 o;
        o.x = fmaf(acc0.x, di, bv.x);
        o.y = fmaf(acc0.y, di, bv.y);
        o.z = fmaf(acc0.z, di, bv.z);
        o.w = fmaf(acc0.w, di, bv.w);
        ((float4*)agg)[(size_t)w * 16 + f4] = o;
    }
}

__device__ __forceinline__ float sigm(float x) { return 1.f / (1.f + __expf(-x)); }
__device__ __forceinline__ float tanhf_(float x) { return 1.f - 2.f / (__expf(2.f * x) + 1.f); }

// LSTM + FC, v2. Block 256 = 4 waves, 32 nodes (8/wave); lane owns k={lane,64+lane}.
// LDS exactly 40960 B -> 4 blocks/CU. Gate weights in 8-way-floor XOR-swizzled
// LDS (r&7). FC via h1->LDS (132-stride pad) + 320 broadcast dot products.
__global__ __launch_bounds__(256) void k_lstm_fc(const float* __restrict__ agg,
                                                 const float* __restrict__ W_ih,
                                                 const float* __restrict__ b_ih,
                                                 const float* __restrict__ b_hh,
                                                 const float* __restrict__ W_fc,
                                                 const float* __restrict__ b_fc,
                                                 float* __restrict__ out, int n) {
    __shared__ float smem[10240];          // 40 KB exactly
    float4* Wl4 = (float4*)smem;           // phase1: [128 r][16 f4] swizzled (32 KB)
    float4* hN4 = (float4*)(smem + 8192);  // phase1: [32 nd][16 f4] (8 KB)
    // phase2 (after sync): h1s = smem[0..4223] ([32 nd][132 pad]), wfcs = smem[4224..5503]
    const int t = threadIdx.x;
    const int wv = t >> 6, lane = t & 63;
    const int node0 = blockIdx.x * 32;
    const float4* A4 = (const float4*)agg;
    const float4* Wih4 = (const float4*)W_ih;

    // combined biases (gates i,g,o = W_ih rows 0,256,384; k = lane, 64+lane)
    const float bi0 = b_ih[lane]       + b_hh[lane];
    const float bi1 = b_ih[64 + lane]  + b_hh[64 + lane];
    const float bg0 = b_ih[256 + lane] + b_hh[256 + lane];
    const float bg1 = b_ih[320 + lane] + b_hh[320 + lane];
    const float bo0 = b_ih[384 + lane] + b_hh[384 + lane];
    const float bo1 = b_ih[448 + lane] + b_hh[448 + lane];

    // stage node features (relu of agg)
    for (int i = t; i < 512; i += 256) {
        int nd = i >> 4;
        float4 v = make_float4(0.f, 0.f, 0.f, 0.f);
        if (node0 + nd < n) {
            v = A4[(size_t)(node0 + nd) * 16 + (i & 15)];
            v.x = fmaxf(v.x, 0.f); v.y = fmaxf(v.y, 0.f);
            v.z = fmaxf(v.z, 0.f); v.w = fmaxf(v.w, 0.f);
        }
        hN4[i] = v;
    }

    float ac[3][2][8];
    #pragma unroll
    for (int g = 0; g < 3; g++)
        #pragma unroll
        for (int h = 0; h < 2; h++)
            #pragma unroll
            for (int q = 0; q < 8; q++) ac[g][h][q] = 0.f;

    const int sw = lane & 7;
    #pragma unroll
    for (int g = 0; g < 3; g++) {
        __syncthreads();
        const int grow0 = (g == 0) ? 0 : ((g + 1) * 128);
        for (int i = t; i < 2048; i += 256) {
            int r = i >> 4, d4 = i & 15;
            Wl4[(r << 4) | (d4 ^ (r & 7))] = Wih4[(size_t)(grow0 + r) * 16 + d4];
        }
        __syncthreads();
        #pragma unroll 2
        for (int j = 0; j < 16; j++) {
            int js = j ^ sw;
            float4 w0 = Wl4[(lane << 4) | js];
            float4 w1 = Wl4[((64 + lane) << 4) | js];
            #pragma unroll
            for (int q = 0; q < 8; q++) {
                float4 hv = hN4[((wv * 8 + q) << 4) | j];
                ac[g][0][q] = fmaf(hv.w, w0.w, fmaf(hv.z, w0.z, fmaf(hv.y, w0.y, fmaf(hv.x, w0.x, ac[g][0][q]))));
                ac[g][1][q] = fmaf(hv.w, w1.w, fmaf(hv.z, w1.z, fmaf(hv.y, w1.y, fmaf(hv.x, w1.x, ac[g][1][q]))));
            }
        }
    }

    __syncthreads();   // gate reads done; smem free for h1s / wfcs

    #pragma unroll
    for (int q = 0; q < 8; q++) {
        int nd = wv * 8 + q;
        float gi0 = ac[0][0][q] + bi0, gg0 = ac[1][0][q] + bg0, go0 = ac[2][0][q] + bo0;
        float gi1 = ac[0][1][q] + bi1, gg1 = ac[1][1][q] + bg1, go1 = ac[2][1][q] + bo1;
        float h1a = sigm(go0) * tanhf_(sigm(gi0) * tanhf_(gg0));
        float h1b = sigm(go1) * tanhf_(sigm(gi1) * tanhf_(gg1));
        smem[nd * 132 + lane]      = h1a;   // k = lane
        smem[nd * 132 + 64 + lane] = h1b;   // k = 64+lane
    }
    float* wfcs = smem + 4224;
    for (int i = t; i < 1280; i += 256) wfcs[i] = W_fc[i];
    __syncthreads();

    // FC: 320 outputs (32 nodes x 10 classes); h1s rows padded to 132 words.
    for (int oc = t; oc < 320; oc += 256) {
        int nd = oc & 31, c = oc >> 5;
        const float4* hrow = (const float4*)&smem[nd * 132];
        const float4* wrow = (const float4*)&wfcs[c * 128];
        float s = 0.f;
        #pragma unroll 8
        for (int k4 = 0; k4 < 32; k4++) {
            float4 h = hrow[k4], w = wrow[k4];
            s = fmaf(h.w, w.w, fmaf(h.z, w.z, fmaf(h.y, w.y, fmaf(h.x, w.x, s))));
        }
        int node = node0 + nd;
        if (node < n) out[(size_t)node * 10 + c] = s + b_fc[c];
    }
}

extern "C" void kernel_launch(void* const* d_in, const int* in_sizes, int n_in,
                              void* d_out, int out_size, void* d_ws, size_t ws_size,
                              hipStream_t stream) {
    const float* x    = (const float*)d_in[0];
    const int*   ei   = (const int*)d_in[1];
    const float* W1   = (const float*)d_in[2];
    const float* b1   = (const float*)d_in[3];
    const float* W2   = (const float*)d_in[4];
    const float* b2   = (const float*)d_in[5];
    const float* W3   = (const float*)d_in[6];
    const float* b3   = (const float*)d_in[7];
    const float* W4   = (const float*)d_in[8];
    const float* b4   = (const float*)d_in[9];
    const float* W5   = (const float*)d_in[10];
    const float* b5   = (const float*)d_in[11];
    const float* W_ih = (const float*)d_in[12];
    // d_in[13] = W_hh: dead (h0 = 0)
    const float* b_ih = (const float*)d_in[14];
    const float* b_hh = (const float*)d_in[15];
    const float* W_fc = (const float*)d_in[16];
    const float* b_fc = (const float*)d_in[17];
    float* out = (float*)d_out;

    const int N = in_sizes[0] / 128;
    const int E = in_sizes[1] / 2;
    const int* row = ei;
    const int* col = ei + E;

    // workspace layout (4-byte units, each region 16B-aligned)
    size_t off = 0;
    auto alloc = [&](size_t elems) { size_t cur = off; off += (elems + 3) & ~(size_t)3; return cur; };
    int*   base_i = (int*)d_ws;
    float* base_f = (float*)d_ws;
    int*   cnt    = base_i + alloc(N);
    int*   rowptr = base_i + alloc((size_t)N + 1);
    int*   cursor = base_i + alloc(N);
    int*   srcidx = base_i + alloc(E);
    int*   bsum   = base_i + alloc(64);
    int*   boff   = base_i + alloc(64);
    float* dinv   = base_f + alloc(N);
    float* WT     = base_f + alloc(24576);
    unsigned short* hWs = (unsigned short*)(base_f + alloc((size_t)N * 32)); // bf16 [N][64]
    float* agg    = base_f + alloc((size_t)N * 64);
    float* WT1 = WT;
    float* WT2 = WT + 8192;
    float* WT3 = WT + 8192 + 4096;
    float* WT4 = WT + 8192 + 8192;
    float* WT5 = WT + 8192 + 12288;

    const int nbE  = (E + 255) / 256;        // 3125
    const int nbGa = (N * 64 + 255) / 256;   // 12500 (wave per node)
    const int nbGe = (N + 31) / 32;          // 1563
    const int nbL  = (N + 31) / 32;          // 1563
    const int nbS  = (N + 1023) / 1024;      // 49 (must be <= 64)

    hipMemsetAsync(cnt, 0, sizeof(int) * N, stream);
    k_transp<<<96, 256, 0, stream>>>(W1, W2, W3, W4, W5, WT);
    k_count<<<nbE, 256, 0, stream>>>(col, cnt, E);
    k_scanA<<<nbS, 256, 0, stream>>>(cnt, bsum, N);
    k_scanB<<<1, 64, 0, stream>>>(bsum, boff, nbS);
    k_scanC<<<nbS, 256, 0, stream>>>(cnt, boff, rowptr, cursor, dinv, N, E);
    k_fill<<<nbE, 256, 0, stream>>>(row, col, cursor, srcidx, E);

    k_gemm2<128, false><<<nbGe, 256, 0, stream>>>(x, WT1, dinv, hWs, N);
    k_gather<<<nbGa, 256, 0, stream>>>(rowptr, srcidx, dinv, b1, hWs, agg, N);
    k_gemm2<64, true><<<nbGe, 256, 0, stream>>>(agg, WT2, dinv, hWs, N);
    k_gather<<<nbGa, 256, 0, stream>>>(rowptr, srcidx, dinv, b2, hWs, agg, N);
    k_gemm2<64, true><<<nbGe, 256, 0, stream>>>(agg, WT3, dinv, hWs, N);
    k_gather<<<nbGa, 256, 0, stream>>>(rowptr, srcidx, dinv, b3, hWs, agg, N);
    k_gemm2<64, true><<<nbGe, 256, 0, stream>>>(agg, WT4, dinv, hWs, N);
    k_gather<<<nbGa, 256, 0, stream>>>(rowptr, srcidx, dinv, b4, hWs, agg, N);
    k_gemm2<64, true><<<nbGe, 256, 0, stream>>>(agg, WT5, dinv, hWs, N);
    k_gather<<<nbGa, 256, 0, stream>>>(rowptr, srcidx, dinv, b5, hWs, agg, N);

    k_lstm_fc<<<nbL, 256, 0, stream>>>(agg, W_ih, b_ih, b_hh, W_fc, b_fc, out, N);
}